// Round 11
// baseline (1973.479 us; speedup 1.0000x reference)
//
#include <hip/hip_runtime.h>

// RNNDoubleStacked: P=4096, F=128 (ragged), H=128.
// R10 post-mortem: fusion works (producers hidden); consumer ~850 cyc/step =
// ~430 chain + ~290 LDS-pipe queue (4 waves x 6 LDS instr after each barrier)
// + 4-wave barrier skew. R11: BOTH paths retiled to 2 waves (T=128):
//   lane=(og,jg): og = wv*8 + (lane>>3) owns 8 outputs; jg = lane&7 owns the
//   16-float h slice [jg*16,+16). 4 rot-decorrelated b128 reads, 128 FMA,
//   3-stage DPP reduce-scatter (keep/ship order makes final output
//   oi = wv*64+lane -> coalesced write/u-read, no duplication).
//   LDS instrs/step: 12 total (was 24). Consumer: single-buffer 32KB U panel,
//   chunk gate on RELEASE/AGENT ready-counters, setprio(1). Producers bump
//   cnt[p>>6] after U-row store + __syncthreads.

constexpr int PN = 4096;
constexpr int FN = 128;
constexpr int HN = 128;
constexpr int CH  = 64;            // particles per chunk = consumer steps/chunk
constexpr int NCH = PN / CH;       // 64 chunks

__device__ __forceinline__ float fast_tanh(float x) {
    float e = __expf(2.0f * x);
    return 1.0f - 2.0f / (e + 1.0f);
}

// Raw workgroup barrier WITHOUT a vmcnt(0) drain.
__device__ __forceinline__ void lds_barrier() {
    asm volatile("s_waitcnt lgkmcnt(0)\n\ts_barrier" ::: "memory");
}

// --- DPP cross-lane ops (VALU; partners within the 16-lane DPP row) ---
__device__ __forceinline__ float dpp_xor1(float x) {
    return __int_as_float(__builtin_amdgcn_update_dpp(
        0, __float_as_int(x), 0xB1, 0xF, 0xF, true));
}
__device__ __forceinline__ float dpp_xor2(float x) {
    return __int_as_float(__builtin_amdgcn_update_dpp(
        0, __float_as_int(x), 0x4E, 0xF, 0xF, true));
}
__device__ __forceinline__ float dpp_xor4(float x, bool hi) {
    int a = __builtin_amdgcn_update_dpp(0, __float_as_int(x), 0x104, 0xF, 0xF, true); // row_shl:4
    int b = __builtin_amdgcn_update_dpp(0, __float_as_int(x), 0x114, 0xF, 0xF, true); // row_shr:4
    return __int_as_float(hi ? b : a);
}

// 3-stage reduce-scatter over the 8 jg lanes with 8 accumulators.
// Keep/ship order: stage k keeps the half matching jg's bit -> final
// accumulator index c == jg, i.e. lane owns output og*8 + jg.
__device__ __forceinline__ float reduce8(const float s[8], int jg) {
    const bool hi4 = (jg & 4) != 0;
    float x0 = (hi4 ? s[4] : s[0]) + dpp_xor4(hi4 ? s[0] : s[4], hi4);
    float x1 = (hi4 ? s[5] : s[1]) + dpp_xor4(hi4 ? s[1] : s[5], hi4);
    float x2 = (hi4 ? s[6] : s[2]) + dpp_xor4(hi4 ? s[2] : s[6], hi4);
    float x3 = (hi4 ? s[7] : s[3]) + dpp_xor4(hi4 ? s[3] : s[7], hi4);
    const bool hi2 = (jg & 2) != 0;
    float y0 = (hi2 ? x2 : x0) + dpp_xor2(hi2 ? x0 : x2);
    float y1 = (hi2 ? x3 : x1) + dpp_xor2(hi2 ? x1 : x3);
    const bool hi1 = (jg & 1) != 0;
    return (hi1 ? y1 : y0) + dpp_xor1(hi1 ? y0 : y1);
}

__device__ __forceinline__ void wait_chunk(const unsigned* cnt, int c) {
    while (__hip_atomic_load(&cnt[c], __ATOMIC_ACQUIRE,
                             __HIP_MEMORY_SCOPE_AGENT) < (unsigned)CH) {
        __builtin_amdgcn_s_sleep(8);
    }
}

// Load w[c][4t+e] = W[(og*8+c)*HN + jg*16 + 4*((t+rot)&3) + e]  (rot baked in).
__device__ __forceinline__ void load_w(const float* W, int og, int jg, int rot,
                                       float w[8][16]) {
    #pragma unroll
    for (int c = 0; c < 8; ++c) {
        const float* row = W + (og * 8 + c) * HN + jg * 16;
        #pragma unroll
        for (int t = 0; t < 4; ++t) {
            const int krot = (t + rot) & 3;
            float4 v = *reinterpret_cast<const float4*>(row + 4 * krot);
            w[c][4*t+0] = v.x; w[c][4*t+1] = v.y;
            w[c][4*t+2] = v.z; w[c][4*t+3] = v.w;
        }
    }
}

// 4 rotated b128 reads + 128 FMAs into s[8].
__device__ __forceinline__ void matvec_slice(const float* base, int rot,
                                             const float w[8][16], float s[8]) {
    #pragma unroll
    for (int t = 0; t < 4; ++t) {
        const int krot = (t + rot) & 3;        // runtime only in the ADDRESS
        float4 hv = *reinterpret_cast<const float4*>(base + 4 * krot);
        #pragma unroll
        for (int c = 0; c < 8; ++c) {
            s[c] = fmaf(w[c][4*t+0], hv.x, s[c]);
            s[c] = fmaf(w[c][4*t+1], hv.y, s[c]);
            s[c] = fmaf(w[c][4*t+2], hv.z, s[c]);
            s[c] = fmaf(w[c][4*t+3], hv.w, s[c]);
        }
    }
}

// ---------------- producer body: net1 for particle p ----------------
template <bool SYNC>
__device__ __forceinline__ void net1_body(
    int p, int tid,
    const float* __restrict__ event,  const int* __restrict__ lengths,
    const float* __restrict__ W_ih1,  const float* __restrict__ W_hh1,
    const float* __restrict__ b_ih1,  const float* __restrict__ b_hh1,
    const float* __restrict__ W_ih2,  const float* __restrict__ b_ih2,
    const float* __restrict__ b_hh2,  float* __restrict__ U,
    unsigned* cnt, float (*h)[HN], float* ev)
{
    const int wv   = tid >> 6;                 // 0..1
    const int lane = tid & 63;
    const int jg   = lane & 7;                 // 16-float slice index
    const int og   = (wv << 3) + (lane >> 3);  // 0..15, 8 outputs each
    const int rot  = jg >> 1;                  // 0..3
    const int oi_w = (wv << 6) + lane;         // = og*8 + jg (coalesced)

    ev[tid]   = event[p * FN + tid];           // T=128=FN
    h[0][tid] = 0.0f;

    float w[8][16];
    load_w(W_hh1, og, jg, rot, w);
    const float wx_own   = W_ih1[oi_w];
    const float bias_own = b_ih1[oi_w] + b_hh1[oi_w];
    const int   len      = lengths[p];

    __syncthreads();

    for (int t = 0; t < len; ++t) {
        const int cur = t & 1;
        const float x = ev[t];                 // b32 broadcast
        float s[8] = {0,0,0,0,0,0,0,0};
        matvec_slice(&h[cur][jg * 16], rot, w, s);
        const float z  = reduce8(s, jg);
        h[cur ^ 1][oi_w] = fast_tanh(z + fmaf(wx_own, x, bias_own));
        lds_barrier();
    }

    // Tail: U[p][i] = h1 . W_ih2_row_i + b_ih2[i] + b_hh2[i]
    {
        const float4* h4 = reinterpret_cast<const float4*>(h[len & 1]);
        const float4* w2 = reinterpret_cast<const float4*>(W_ih2 + tid * HN);
        float a0 = b_ih2[tid] + b_hh2[tid], a1 = 0.f, a2 = 0.f, a3 = 0.f;
        #pragma unroll
        for (int k = 0; k < HN / 4; ++k) {
            float4 hv = h4[k];
            float4 wv2 = w2[k];
            a0 = fmaf(wv2.x, hv.x, a0);
            a1 = fmaf(wv2.y, hv.y, a1);
            a2 = fmaf(wv2.z, hv.z, a2);
            a3 = fmaf(wv2.w, hv.w, a3);
        }
        U[p * HN + tid] = (a0 + a1) + (a2 + a3);
    }

    if (SYNC) {
        __syncthreads();   // drain U stores (vmcnt 0) before the count bump
        if (tid == 0) {
            __hip_atomic_fetch_add(&cnt[p >> 6], 1u,
                                   __ATOMIC_RELEASE, __HIP_MEMORY_SCOPE_AGENT);
        }
    }
}

// ---------------- consumer body: net2 ----------------
template <bool SYNC>
__device__ __forceinline__ void net2_body(
    int tid,
    const float* __restrict__ U, const float* __restrict__ W_hh2,
    float* __restrict__ out, const unsigned* cnt,
    float (*h)[HN], float* Ulds)
{
    const int wv   = tid >> 6;                 // 0..1
    const int lane = tid & 63;
    const int jg   = lane & 7;
    const int og   = (wv << 3) + (lane >> 3);
    const int rot  = jg >> 1;
    const int oi_w = (wv << 6) + lane;         // coalesced write/u-read

    __builtin_amdgcn_s_setprio(1);             // win CU arbitration vs producers

    float w[8][16];
    load_w(W_hh2, og, jg, rot, w);

    if (SYNC) wait_chunk(cnt, 0);
    {   // stage chunk 0 (16 float4 per lane, coalesced)
        const float4* g = reinterpret_cast<const float4*>(U);
        float4*       l = reinterpret_cast<float4*>(Ulds);
        #pragma unroll
        for (int r = 0; r < 16; ++r) l[r * 128 + tid] = g[r * 128 + tid];
    }
    h[0][tid] = 0.0f;
    __syncthreads();

    for (int c = 0; c < NCH; ++c) {
        const bool has_next = (c + 1 < NCH);
        if (SYNC && has_next) wait_chunk(cnt, c + 1);

        // Issue-early: next chunk into registers; in flight across the chunk.
        float4 st[16];
        {
            const float4* gsrc = reinterpret_cast<const float4*>(
                U + (has_next ? (c + 1) : c) * CH * HN);
            #pragma unroll
            for (int r = 0; r < 16; ++r) st[r] = gsrc[r * 128 + tid];
        }

        for (int s2 = 0; s2 < CH; ++s2) {
            const int hc = s2 & 1;
            const float u_cur = Ulds[s2 * HN + oi_w];   // coalesced b32
            float s[8] = {0,0,0,0,0,0,0,0};
            matvec_slice(&h[hc][jg * 16], rot, w, s);
            const float z = reduce8(s, jg);
            h[hc ^ 1][oi_w] = fast_tanh(z + u_cur);
            lds_barrier();                     // lgkm-only: staging stays in flight
        }

        // Write-late: publish next panel (vmcnt wait ~free after 64 steps).
        if (has_next) {
            float4* ldst = reinterpret_cast<float4*>(Ulds);
            #pragma unroll
            for (int r = 0; r < 16; ++r) ldst[r * 128 + tid] = st[r];
        }
        lds_barrier();
    }

    out[tid] = h[0][tid];                      // each chunk ends at parity 0
}

// ---------------- kernels ----------------
__global__ __launch_bounds__(128, 2) void fused_kernel(
    const float* __restrict__ event,  const int* __restrict__ lengths,
    const float* __restrict__ W_ih1,  const float* __restrict__ W_hh1,
    const float* __restrict__ b_ih1,  const float* __restrict__ b_hh1,
    const float* __restrict__ W_ih2,  const float* __restrict__ W_hh2,
    const float* __restrict__ b_ih2,  const float* __restrict__ b_hh2,
    float* __restrict__ U, float* __restrict__ out, unsigned* cnt)
{
    __shared__ float h[2][HN];
    __shared__ float ev[FN];                   // producer only
    __shared__ float Ulds[CH * HN];            // consumer only (32 KB)

    const int tid = threadIdx.x;
    if (blockIdx.x == 0) {
        net2_body<true>(tid, U, W_hh2, out, cnt, h, Ulds);
    } else {
        net1_body<true>(blockIdx.x - 1, tid, event, lengths, W_ih1, W_hh1,
                        b_ih1, b_hh1, W_ih2, b_ih2, b_hh2, U, cnt, h, ev);
    }
}

__global__ __launch_bounds__(128, 2) void net1_only(
    const float* __restrict__ event,  const int* __restrict__ lengths,
    const float* __restrict__ W_ih1,  const float* __restrict__ W_hh1,
    const float* __restrict__ b_ih1,  const float* __restrict__ b_hh1,
    const float* __restrict__ W_ih2,  const float* __restrict__ b_ih2,
    const float* __restrict__ b_hh2,  float* __restrict__ U)
{
    __shared__ float h[2][HN];
    __shared__ float ev[FN];
    net1_body<false>(blockIdx.x, threadIdx.x, event, lengths, W_ih1, W_hh1,
                     b_ih1, b_hh1, W_ih2, b_ih2, b_hh2, U, nullptr, h, ev);
}

__global__ __launch_bounds__(128, 2) void net2_only(
    const float* __restrict__ U, const float* __restrict__ W_hh2,
    float* __restrict__ out)
{
    __shared__ float h[2][HN];
    __shared__ float Ulds[CH * HN];
    net2_body<false>(threadIdx.x, U, W_hh2, out, nullptr, h, Ulds);
}

extern "C" void kernel_launch(void* const* d_in, const int* in_sizes, int n_in,
                              void* d_out, int out_size, void* d_ws, size_t ws_size,
                              hipStream_t stream)
{
    const float* event   = (const float*)d_in[0];
    const int*   lengths = (const int*)  d_in[1];
    const float* W_ih1   = (const float*)d_in[2];
    const float* W_hh1   = (const float*)d_in[3];
    const float* b_ih1   = (const float*)d_in[4];
    const float* b_hh1   = (const float*)d_in[5];
    const float* W_ih2   = (const float*)d_in[6];
    const float* W_hh2   = (const float*)d_in[7];
    const float* b_ih2   = (const float*)d_in[8];
    const float* b_hh2   = (const float*)d_in[9];
    float* out = (float*)d_out;                   // 128 floats
    float* U   = (float*)d_ws;                    // PN*HN floats = 2 MB
    unsigned* cnt = (unsigned*)(U + (size_t)PN * HN);

    const bool sync_ok =
        ws_size >= (size_t)PN * HN * sizeof(float) + NCH * sizeof(unsigned);

    if (sync_ok) {
        hipMemsetAsync(cnt, 0, NCH * sizeof(unsigned), stream);  // clear poison
        fused_kernel<<<dim3(PN + 1), dim3(128), 0, stream>>>(
            event, lengths, W_ih1, W_hh1, b_ih1, b_hh1,
            W_ih2, W_hh2, b_ih2, b_hh2, U, out, cnt);
    } else {
        net1_only<<<dim3(PN), dim3(128), 0, stream>>>(
            event, lengths, W_ih1, W_hh1, b_ih1, b_hh1, W_ih2, b_ih2, b_hh2, U);
        net2_only<<<dim3(1), dim3(128), 0, stream>>>(U, W_hh2, out);
    }
}

// Round 13
// 1833.080 us; speedup vs baseline: 1.0766x; 1.0766x over previous
//
#include <hip/hip_runtime.h>

// RNNDoubleStacked: P=4096, F=128 (ragged), H=128.
// R12 post-mortem: "full dot per lane" was structurally wrong (needs 32 b128
// reads/lane -> LDS-pipe explosion; and as written read only h[0..31] ->
// absmax 0.132). REVERT to R10 fused (1494us, absmax 0) + ONE change:
// consumer matvec uses v_pk_fma_f32 (packed fp32, 2 MACs/instr) -> per-wave
// FMA issue 128->64 cyc. Weights packed to float2 at load (same rotation),
// 4 float2 accumulators, unchanged 3-stage DPP reduce-scatter. Producers
// byte-identical to R10.
//   block 0    = consumer (net2, 4 waves, jg8 slices, chunked 32KB U panel,
//                RELEASE/AGENT ready-counter gate, setprio(1))
//   blocks 1.. = producers (net1, jg16/reduce16, bump cnt[p>>6] post-store)

constexpr int PN = 4096;
constexpr int FN = 128;
constexpr int HN = 128;
constexpr int CH  = 64;            // particles per chunk = consumer steps/chunk
constexpr int NCH = PN / CH;       // 64 chunks

__device__ __forceinline__ float fast_tanh(float x) {
    float e = __expf(2.0f * x);
    return 1.0f - 2.0f / (e + 1.0f);
}

// Raw workgroup barrier WITHOUT a vmcnt(0) drain.
__device__ __forceinline__ void lds_barrier() {
    asm volatile("s_waitcnt lgkmcnt(0)\n\ts_barrier" ::: "memory");
}

// Packed fp32 FMA: a.xy = b.xy * c.xy + a.xy (one VOP3P instruction).
__device__ __forceinline__ void pk_fma(float2& a, float2 b, float2 c) {
    asm("v_pk_fma_f32 %0, %1, %2, %0" : "+v"(a) : "v"(b), "v"(c));
}

// --- DPP cross-lane ops (VALU; partners within the 16-lane DPP row) ---
__device__ __forceinline__ float dpp_xor1(float x) {
    return __int_as_float(__builtin_amdgcn_update_dpp(
        0, __float_as_int(x), 0xB1, 0xF, 0xF, true));
}
__device__ __forceinline__ float dpp_xor2(float x) {
    return __int_as_float(__builtin_amdgcn_update_dpp(
        0, __float_as_int(x), 0x4E, 0xF, 0xF, true));
}
__device__ __forceinline__ float dpp_xor4(float x, bool hi) {
    int a = __builtin_amdgcn_update_dpp(0, __float_as_int(x), 0x104, 0xF, 0xF, true);
    int b = __builtin_amdgcn_update_dpp(0, __float_as_int(x), 0x114, 0xF, 0xF, true);
    return __int_as_float(hi ? b : a);
}
__device__ __forceinline__ float dpp_xor8(float x, bool hi) {
    int a = __builtin_amdgcn_update_dpp(0, __float_as_int(x), 0x108, 0xF, 0xF, true);
    int b = __builtin_amdgcn_update_dpp(0, __float_as_int(x), 0x118, 0xF, 0xF, true);
    return __int_as_float(hi ? b : a);
}

// 16-lane reduce-scatter over 8 accumulators (producer tiling).
__device__ __forceinline__ float reduce16(const float s[8], int jg) {
    const bool hi8 = (jg & 8) != 0;
    float m0 = hi8 ? s[0] : s[4], k0 = hi8 ? s[4] : s[0];
    float m1 = hi8 ? s[1] : s[5], k1 = hi8 ? s[5] : s[1];
    float m2 = hi8 ? s[2] : s[6], k2 = hi8 ? s[6] : s[2];
    float m3 = hi8 ? s[3] : s[7], k3 = hi8 ? s[7] : s[3];
    float x0 = k0 + dpp_xor8(m0, hi8);
    float x1 = k1 + dpp_xor8(m1, hi8);
    float x2 = k2 + dpp_xor8(m2, hi8);
    float x3 = k3 + dpp_xor8(m3, hi8);
    const bool hi4 = (jg & 4) != 0;
    float y0 = (hi4 ? x2 : x0) + dpp_xor4(hi4 ? x0 : x2, hi4);
    float y1 = (hi4 ? x3 : x1) + dpp_xor4(hi4 ? x1 : x3, hi4);
    const bool hi2 = (jg & 2) != 0;
    float z  = (hi2 ? y1 : y0) + dpp_xor2(hi2 ? y0 : y1);
    z += dpp_xor1(z);
    return z;
}
__device__ __forceinline__ int reduce16_cidx(int jg) {
    return ((jg >> 3) & 1) * 4 + ((jg >> 2) & 1) * 2 + ((jg >> 1) & 1);
}

__device__ __forceinline__ void wait_chunk(const unsigned* cnt, int c) {
    while (__hip_atomic_load(&cnt[c], __ATOMIC_ACQUIRE,
                             __HIP_MEMORY_SCOPE_AGENT) < (unsigned)CH) {
        __builtin_amdgcn_s_sleep(8);           // ~512 cyc backoff per poll
    }
}

// ---------------- producer body: net1 for particle p (R10-proven) ----------------
template <bool SYNC>
__device__ __forceinline__ void net1_body(
    int p, int tid,
    const float* __restrict__ event,  const int* __restrict__ lengths,
    const float* __restrict__ W_ih1,  const float* __restrict__ W_hh1,
    const float* __restrict__ b_ih1,  const float* __restrict__ b_hh1,
    const float* __restrict__ W_ih2,  const float* __restrict__ b_ih2,
    const float* __restrict__ b_hh2,  float* __restrict__ U,
    unsigned* cnt, float (*h)[HN], float* ev)
{
    const int wv   = tid >> 6;
    const int lane = tid & 63;
    const int jg   = lane & 15;                // 8-float inner slice
    const int og16 = (wv << 2) + (lane >> 4);  // 16 groups x 8 outputs
    const int rot  = (jg >> 2) & 1;
    const int oi_w = og16 * 8 + reduce16_cidx(jg);

    if (tid < FN) ev[tid]   = event[p * FN + tid];
    if (tid < HN) h[0][tid] = 0.0f;

    float w[8][8];
    #pragma unroll
    for (int c = 0; c < 8; ++c) {
        const float* row = W_hh1 + (og16 * 8 + c) * HN + jg * 8;
        #pragma unroll
        for (int t = 0; t < 2; ++t) {
            const int krot = (t + rot) & 1;
            float4 v = *reinterpret_cast<const float4*>(row + 4 * krot);
            w[c][4*t+0] = v.x; w[c][4*t+1] = v.y;
            w[c][4*t+2] = v.z; w[c][4*t+3] = v.w;
        }
    }
    const float wx_own   = W_ih1[oi_w];
    const float bias_own = b_ih1[oi_w] + b_hh1[oi_w];
    const int   len      = lengths[p];

    __syncthreads();

    for (int t = 0; t < len; ++t) {
        const int cur = t & 1;
        const float x = ev[t];
        const float* base = &h[cur][jg * 8];
        float s[8] = {0,0,0,0,0,0,0,0};
        #pragma unroll
        for (int tt = 0; tt < 2; ++tt) {
            const int krot = (tt + rot) & 1;
            float4 hv = *reinterpret_cast<const float4*>(base + 4 * krot);
            #pragma unroll
            for (int c = 0; c < 8; ++c) {
                s[c] = fmaf(w[c][4*tt+0], hv.x, s[c]);
                s[c] = fmaf(w[c][4*tt+1], hv.y, s[c]);
                s[c] = fmaf(w[c][4*tt+2], hv.z, s[c]);
                s[c] = fmaf(w[c][4*tt+3], hv.w, s[c]);
            }
        }
        const float z  = reduce16(s, jg);
        const float hn = fast_tanh(z + fmaf(wx_own, x, bias_own));
        if ((jg & 1) == 0) h[cur ^ 1][oi_w] = hn;
        lds_barrier();
    }

    // Tail: U[p][i] = h1 . W_ih2_row_i + b_ih2[i] + b_hh2[i]
    if (tid < HN) {
        const float4* h4 = reinterpret_cast<const float4*>(h[len & 1]);
        const float4* w2 = reinterpret_cast<const float4*>(W_ih2 + tid * HN);
        float a0 = b_ih2[tid] + b_hh2[tid], a1 = 0.f, a2 = 0.f, a3 = 0.f;
        #pragma unroll
        for (int k = 0; k < HN / 4; ++k) {
            float4 hv = h4[k];
            float4 wv = w2[k];
            a0 = fmaf(wv.x, hv.x, a0);
            a1 = fmaf(wv.y, hv.y, a1);
            a2 = fmaf(wv.z, hv.z, a2);
            a3 = fmaf(wv.w, hv.w, a3);
        }
        U[p * HN + tid] = (a0 + a1) + (a2 + a3);
    }

    if (SYNC) {
        __syncthreads();   // full drain: every wave's U stores visible pre-count
        if (tid == 0) {
            __hip_atomic_fetch_add(&cnt[p >> 6], 1u,
                                   __ATOMIC_RELEASE, __HIP_MEMORY_SCOPE_AGENT);
        }
    }
}

// ---------------- consumer body: net2 (R10 dataflow + pk_fma matvec) ----------------
template <bool SYNC>
__device__ __forceinline__ void net2_body(
    int tid,
    const float* __restrict__ U, const float* __restrict__ W_hh2,
    float* __restrict__ out, const unsigned* cnt,
    float (*h)[HN], float* Ulds)
{
    const int wv   = tid >> 6;
    const int lane = tid & 63;
    const int jg   = lane & 7;                 // 16-float inner slice
    const int ogl  = lane >> 3;
    const int og   = (wv << 3) + ogl;          // 32 groups x 4 outputs
    const int rot  = jg >> 1;
    const bool hi4 = (jg & 4) != 0;
    const int cidx = ((jg >> 2) & 1) * 2 + ((jg >> 1) & 1);
    const int oi_w = og * 4 + cidx;

    __builtin_amdgcn_s_setprio(1);             // win CU arbitration vs producers

    // Packed weights: wp[c][2t+j] covers the same rotated float4 slots as R10's
    // w[c][4t+e] (slot t reads h words jg*16 + 4*((t+rot)&3) + e).
    float2 wp[4][8];
    #pragma unroll
    for (int c = 0; c < 4; ++c) {
        const float* row = W_hh2 + (og * 4 + c) * HN + jg * 16;
        #pragma unroll
        for (int t = 0; t < 4; ++t) {
            const int krot = (t + rot) & 3;
            float4 v = *reinterpret_cast<const float4*>(row + 4 * krot);
            wp[c][2*t+0] = make_float2(v.x, v.y);
            wp[c][2*t+1] = make_float2(v.z, v.w);
        }
    }

    if (SYNC) wait_chunk(cnt, 0);
    {   // stage chunk 0
        const float4* g = reinterpret_cast<const float4*>(U);
        float4*       l = reinterpret_cast<float4*>(Ulds);
        #pragma unroll
        for (int r = 0; r < 8; ++r) l[r * 256 + tid] = g[r * 256 + tid];
    }
    if (tid < HN) h[0][tid] = 0.0f;
    __syncthreads();

    for (int c = 0; c < NCH; ++c) {
        const bool has_next = (c + 1 < NCH);
        if (SYNC && has_next) wait_chunk(cnt, c + 1);

        // Issue-early: next chunk into registers; in flight across the chunk.
        float4 st[8];
        {
            const float4* gsrc = reinterpret_cast<const float4*>(
                U + (has_next ? (c + 1) : c) * CH * HN);
            #pragma unroll
            for (int r = 0; r < 8; ++r) st[r] = gsrc[r * 256 + tid];
        }

        for (int s2 = 0; s2 < CH; ++s2) {
            const int hc = s2 & 1;
            const float u_cur = Ulds[s2 * HN + oi_w];

            // 4 rotated b128 reads; 2 pk_fma per read per output c
            // (4 slots x 2 pk x 4 c = 32 pk = 64 MACs over this lane's
            //  16-float slice; x8 jg slices = full 128-dot).  [R12 lesson:
            //  count MACs/lane x lanes before trusting a new dataflow.]
            const float* base = &h[hc][jg * 16];
            float2 a0 = make_float2(0.f, 0.f), a1 = make_float2(0.f, 0.f);
            float2 a2 = make_float2(0.f, 0.f), a3 = make_float2(0.f, 0.f);
            #pragma unroll
            for (int t = 0; t < 4; ++t) {
                const int krot = (t + rot) & 3;    // runtime only in the ADDRESS
                float4 hv = *reinterpret_cast<const float4*>(base + 4 * krot);
                const float2 hxy = make_float2(hv.x, hv.y);
                const float2 hzw = make_float2(hv.z, hv.w);
                pk_fma(a0, wp[0][2*t+0], hxy); pk_fma(a0, wp[0][2*t+1], hzw);
                pk_fma(a1, wp[1][2*t+0], hxy); pk_fma(a1, wp[1][2*t+1], hzw);
                pk_fma(a2, wp[2][2*t+0], hxy); pk_fma(a2, wp[2][2*t+1], hzw);
                pk_fma(a3, wp[3][2*t+0], hxy); pk_fma(a3, wp[3][2*t+1], hzw);
            }
            float s0  = a0.x + a0.y;
            float s1  = a1.x + a1.y;
            float s2a = a2.x + a2.y;
            float s3  = a3.x + a3.y;

            // 3-stage DPP reduce-scatter over the 8 jg lanes (unchanged).
            const bool lo4 = !hi4;
            float t0 = lo4 ? s2a : s0;
            float t1 = lo4 ? s3  : s1;
            float x0 = (lo4 ? s0 : s2a) + dpp_xor4(t0, hi4);
            float x1 = (lo4 ? s1 : s3 ) + dpp_xor4(t1, hi4);
            const bool lo2 = (jg & 2) == 0;
            float t2 = lo2 ? x1 : x0;
            float z  = (lo2 ? x0 : x1) + dpp_xor2(t2);
            z += dpp_xor1(z);

            const float hn = fast_tanh(z + u_cur);
            if ((jg & 1) == 0) h[hc ^ 1][oi_w] = hn;
            lds_barrier();                     // lgkm-only: staging stays in flight
        }
        // After the final per-step barrier every wave's chunk-c reads are done
        // -> safe to overwrite the single panel. vmcnt wait on st is ~free.
        if (has_next) {
            float4* ldst = reinterpret_cast<float4*>(Ulds);
            #pragma unroll
            for (int r = 0; r < 8; ++r) ldst[r * 256 + tid] = st[r];
        }
        lds_barrier();                         // publish panel for chunk c+1
    }

    if (tid < HN) out[tid] = h[0][tid];        // each chunk ends at parity 0
}

// ---------------- kernels ----------------
__global__ __launch_bounds__(256) void fused_kernel(
    const float* __restrict__ event,  const int* __restrict__ lengths,
    const float* __restrict__ W_ih1,  const float* __restrict__ W_hh1,
    const float* __restrict__ b_ih1,  const float* __restrict__ b_hh1,
    const float* __restrict__ W_ih2,  const float* __restrict__ W_hh2,
    const float* __restrict__ b_ih2,  const float* __restrict__ b_hh2,
    float* __restrict__ U, float* __restrict__ out, unsigned* cnt)
{
    __shared__ float h[2][HN];                 // both paths
    __shared__ float ev[FN];                   // producer only
    __shared__ float Ulds[CH * HN];            // consumer only (32 KB)

    const int tid = threadIdx.x;
    if (blockIdx.x == 0) {
        net2_body<true>(tid, U, W_hh2, out, cnt, h, Ulds);
    } else {
        net1_body<true>(blockIdx.x - 1, tid, event, lengths, W_ih1, W_hh1,
                        b_ih1, b_hh1, W_ih2, b_ih2, b_hh2, U, cnt, h, ev);
    }
}

__global__ __launch_bounds__(256) void net1_only(
    const float* __restrict__ event,  const int* __restrict__ lengths,
    const float* __restrict__ W_ih1,  const float* __restrict__ W_hh1,
    const float* __restrict__ b_ih1,  const float* __restrict__ b_hh1,
    const float* __restrict__ W_ih2,  const float* __restrict__ b_ih2,
    const float* __restrict__ b_hh2,  float* __restrict__ U)
{
    __shared__ float h[2][HN];
    __shared__ float ev[FN];
    net1_body<false>(blockIdx.x, threadIdx.x, event, lengths, W_ih1, W_hh1,
                     b_ih1, b_hh1, W_ih2, b_ih2, b_hh2, U, nullptr, h, ev);
}

__global__ __launch_bounds__(256) void net2_only(
    const float* __restrict__ U, const float* __restrict__ W_hh2,
    float* __restrict__ out)
{
    __shared__ float h[2][HN];
    __shared__ float Ulds[CH * HN];
    net2_body<false>(threadIdx.x, U, W_hh2, out, nullptr, h, Ulds);
}

extern "C" void kernel_launch(void* const* d_in, const int* in_sizes, int n_in,
                              void* d_out, int out_size, void* d_ws, size_t ws_size,
                              hipStream_t stream)
{
    const float* event   = (const float*)d_in[0];
    const int*   lengths = (const int*)  d_in[1];
    const float* W_ih1   = (const float*)d_in[2];
    const float* W_hh1   = (const float*)d_in[3];
    const float* b_ih1   = (const float*)d_in[4];
    const float* b_hh1   = (const float*)d_in[5];
    const float* W_ih2   = (const float*)d_in[6];
    const float* W_hh2   = (const float*)d_in[7];
    const float* b_ih2   = (const float*)d_in[8];
    const float* b_hh2   = (const float*)d_in[9];
    float* out = (float*)d_out;                   // 128 floats
    float* U   = (float*)d_ws;                    // PN*HN floats = 2 MB
    unsigned* cnt = (unsigned*)(U + (size_t)PN * HN);

    const bool sync_ok =
        ws_size >= (size_t)PN * HN * sizeof(float) + NCH * sizeof(unsigned);

    if (sync_ok) {
        hipMemsetAsync(cnt, 0, NCH * sizeof(unsigned), stream);  // clear poison
        fused_kernel<<<dim3(PN + 1), dim3(256), 0, stream>>>(
            event, lengths, W_ih1, W_hh1, b_ih1, b_hh1,
            W_ih2, W_hh2, b_ih2, b_hh2, U, out, cnt);
    } else {
        net1_only<<<dim3(PN), dim3(256), 0, stream>>>(
            event, lengths, W_ih1, W_hh1, b_ih1, b_hh1, W_ih2, b_ih2, b_hh2, U);
        net2_only<<<dim3(1), dim3(256), 0, stream>>>(U, W_hh2, out);
    }
}

// Round 15
// 1531.474 us; speedup vs baseline: 1.2886x; 1.1969x over previous
//
#include <hip/hip_runtime.h>

// RNNDoubleStacked: P=4096, F=128 (ragged), H=128.
// R13 post-mortem: pk_fma asm regressed (+276us) -> consumer is NOT issue-bound;
// asm disrupted ds_read/FMA interleaving. Consumer reverted to R10's proven
// scalar matvec (fused 1494us, absmax 0). ONE new change: pad fused kernel's
// LDS to 82.3KB -> 1 block/CU, evicting producer blocks from the consumer's CU
// (R10 interference: fused 1494 vs standalone 1432 ~= 60us). Producers drop to
// 1/CU too, but they were CU-sharing-throttled; ~340us aggregate, still hidden.
//   block 0    = consumer (net2, 4 waves, jg8 slices, chunked 32KB U panel,
//                RELEASE/AGENT ready-counter gate, setprio(1))
//   blocks 1.. = producers (net1, jg16/reduce16, bump cnt[p>>6] post-store)
// (R14 was an infra failure - GPUAcquisitionTimeout; identical resubmit.)

constexpr int PN = 4096;
constexpr int FN = 128;
constexpr int HN = 128;
constexpr int CH  = 64;            // particles per chunk = consumer steps/chunk
constexpr int NCH = PN / CH;       // 64 chunks
constexpr int PADF = 12000;        // LDS pad floats: total 82304 B > 80KB -> 1 block/CU

__device__ __forceinline__ float fast_tanh(float x) {
    float e = __expf(2.0f * x);
    return 1.0f - 2.0f / (e + 1.0f);
}

// Raw workgroup barrier WITHOUT a vmcnt(0) drain.
__device__ __forceinline__ void lds_barrier() {
    asm volatile("s_waitcnt lgkmcnt(0)\n\ts_barrier" ::: "memory");
}

// --- DPP cross-lane ops (VALU; partners within the 16-lane DPP row) ---
__device__ __forceinline__ float dpp_xor1(float x) {
    return __int_as_float(__builtin_amdgcn_update_dpp(
        0, __float_as_int(x), 0xB1, 0xF, 0xF, true));
}
__device__ __forceinline__ float dpp_xor2(float x) {
    return __int_as_float(__builtin_amdgcn_update_dpp(
        0, __float_as_int(x), 0x4E, 0xF, 0xF, true));
}
__device__ __forceinline__ float dpp_xor4(float x, bool hi) {
    int a = __builtin_amdgcn_update_dpp(0, __float_as_int(x), 0x104, 0xF, 0xF, true);
    int b = __builtin_amdgcn_update_dpp(0, __float_as_int(x), 0x114, 0xF, 0xF, true);
    return __int_as_float(hi ? b : a);
}
__device__ __forceinline__ float dpp_xor8(float x, bool hi) {
    int a = __builtin_amdgcn_update_dpp(0, __float_as_int(x), 0x108, 0xF, 0xF, true);
    int b = __builtin_amdgcn_update_dpp(0, __float_as_int(x), 0x118, 0xF, 0xF, true);
    return __int_as_float(hi ? b : a);
}

// 16-lane reduce-scatter over 8 accumulators (producer tiling).
__device__ __forceinline__ float reduce16(const float s[8], int jg) {
    const bool hi8 = (jg & 8) != 0;
    float m0 = hi8 ? s[0] : s[4], k0 = hi8 ? s[4] : s[0];
    float m1 = hi8 ? s[1] : s[5], k1 = hi8 ? s[5] : s[1];
    float m2 = hi8 ? s[2] : s[6], k2 = hi8 ? s[6] : s[2];
    float m3 = hi8 ? s[3] : s[7], k3 = hi8 ? s[7] : s[3];
    float x0 = k0 + dpp_xor8(m0, hi8);
    float x1 = k1 + dpp_xor8(m1, hi8);
    float x2 = k2 + dpp_xor8(m2, hi8);
    float x3 = k3 + dpp_xor8(m3, hi8);
    const bool hi4 = (jg & 4) != 0;
    float y0 = (hi4 ? x2 : x0) + dpp_xor4(hi4 ? x0 : x2, hi4);
    float y1 = (hi4 ? x3 : x1) + dpp_xor4(hi4 ? x1 : x3, hi4);
    const bool hi2 = (jg & 2) != 0;
    float z  = (hi2 ? y1 : y0) + dpp_xor2(hi2 ? y0 : y1);
    z += dpp_xor1(z);
    return z;
}
__device__ __forceinline__ int reduce16_cidx(int jg) {
    return ((jg >> 3) & 1) * 4 + ((jg >> 2) & 1) * 2 + ((jg >> 1) & 1);
}

__device__ __forceinline__ void wait_chunk(const unsigned* cnt, int c) {
    while (__hip_atomic_load(&cnt[c], __ATOMIC_ACQUIRE,
                             __HIP_MEMORY_SCOPE_AGENT) < (unsigned)CH) {
        __builtin_amdgcn_s_sleep(8);           // ~512 cyc backoff per poll
    }
}

// ---------------- producer body: net1 for particle p (R10-proven) ----------------
template <bool SYNC>
__device__ __forceinline__ void net1_body(
    int p, int tid,
    const float* __restrict__ event,  const int* __restrict__ lengths,
    const float* __restrict__ W_ih1,  const float* __restrict__ W_hh1,
    const float* __restrict__ b_ih1,  const float* __restrict__ b_hh1,
    const float* __restrict__ W_ih2,  const float* __restrict__ b_ih2,
    const float* __restrict__ b_hh2,  float* __restrict__ U,
    unsigned* cnt, float (*h)[HN], float* ev)
{
    const int wv   = tid >> 6;
    const int lane = tid & 63;
    const int jg   = lane & 15;                // 8-float inner slice
    const int og16 = (wv << 2) + (lane >> 4);  // 16 groups x 8 outputs
    const int rot  = (jg >> 2) & 1;
    const int oi_w = og16 * 8 + reduce16_cidx(jg);

    if (tid < FN) ev[tid]   = event[p * FN + tid];
    if (tid < HN) h[0][tid] = 0.0f;

    float w[8][8];
    #pragma unroll
    for (int c = 0; c < 8; ++c) {
        const float* row = W_hh1 + (og16 * 8 + c) * HN + jg * 8;
        #pragma unroll
        for (int t = 0; t < 2; ++t) {
            const int krot = (t + rot) & 1;
            float4 v = *reinterpret_cast<const float4*>(row + 4 * krot);
            w[c][4*t+0] = v.x; w[c][4*t+1] = v.y;
            w[c][4*t+2] = v.z; w[c][4*t+3] = v.w;
        }
    }
    const float wx_own   = W_ih1[oi_w];
    const float bias_own = b_ih1[oi_w] + b_hh1[oi_w];
    const int   len      = lengths[p];

    __syncthreads();

    for (int t = 0; t < len; ++t) {
        const int cur = t & 1;
        const float x = ev[t];
        const float* base = &h[cur][jg * 8];
        float s[8] = {0,0,0,0,0,0,0,0};
        #pragma unroll
        for (int tt = 0; tt < 2; ++tt) {
            const int krot = (tt + rot) & 1;
            float4 hv = *reinterpret_cast<const float4*>(base + 4 * krot);
            #pragma unroll
            for (int c = 0; c < 8; ++c) {
                s[c] = fmaf(w[c][4*tt+0], hv.x, s[c]);
                s[c] = fmaf(w[c][4*tt+1], hv.y, s[c]);
                s[c] = fmaf(w[c][4*tt+2], hv.z, s[c]);
                s[c] = fmaf(w[c][4*tt+3], hv.w, s[c]);
            }
        }
        const float z  = reduce16(s, jg);
        const float hn = fast_tanh(z + fmaf(wx_own, x, bias_own));
        if ((jg & 1) == 0) h[cur ^ 1][oi_w] = hn;
        lds_barrier();
    }

    // Tail: U[p][i] = h1 . W_ih2_row_i + b_ih2[i] + b_hh2[i]
    if (tid < HN) {
        const float4* h4 = reinterpret_cast<const float4*>(h[len & 1]);
        const float4* w2 = reinterpret_cast<const float4*>(W_ih2 + tid * HN);
        float a0 = b_ih2[tid] + b_hh2[tid], a1 = 0.f, a2 = 0.f, a3 = 0.f;
        #pragma unroll
        for (int k = 0; k < HN / 4; ++k) {
            float4 hv = h4[k];
            float4 wv = w2[k];
            a0 = fmaf(wv.x, hv.x, a0);
            a1 = fmaf(wv.y, hv.y, a1);
            a2 = fmaf(wv.z, hv.z, a2);
            a3 = fmaf(wv.w, hv.w, a3);
        }
        U[p * HN + tid] = (a0 + a1) + (a2 + a3);
    }

    if (SYNC) {
        __syncthreads();   // full drain: every wave's U stores visible pre-count
        if (tid == 0) {
            __hip_atomic_fetch_add(&cnt[p >> 6], 1u,
                                   __ATOMIC_RELEASE, __HIP_MEMORY_SCOPE_AGENT);
        }
    }
}

// ---------------- consumer body: net2 (R10-proven scalar matvec) ----------------
template <bool SYNC>
__device__ __forceinline__ void net2_body(
    int tid,
    const float* __restrict__ U, const float* __restrict__ W_hh2,
    float* __restrict__ out, const unsigned* cnt,
    float (*h)[HN], float* Ulds)
{
    const int wv   = tid >> 6;
    const int lane = tid & 63;
    const int jg   = lane & 7;                 // 16-float inner slice
    const int ogl  = lane >> 3;
    const int og   = (wv << 3) + ogl;          // 32 groups x 4 outputs
    const int rot  = jg >> 1;
    const bool hi4 = (jg & 4) != 0;
    const int cidx = ((jg >> 2) & 1) * 2 + ((jg >> 1) & 1);
    const int oi_w = og * 4 + cidx;

    __builtin_amdgcn_s_setprio(1);             // win CU arbitration

    float w[4][16];
    #pragma unroll
    for (int c = 0; c < 4; ++c) {
        const float* row = W_hh2 + (og * 4 + c) * HN + jg * 16;
        #pragma unroll
        for (int t = 0; t < 4; ++t) {
            const int krot = (t + rot) & 3;
            float4 v = *reinterpret_cast<const float4*>(row + 4 * krot);
            w[c][4*t+0] = v.x; w[c][4*t+1] = v.y;
            w[c][4*t+2] = v.z; w[c][4*t+3] = v.w;
        }
    }

    if (SYNC) wait_chunk(cnt, 0);
    {   // stage chunk 0
        const float4* g = reinterpret_cast<const float4*>(U);
        float4*       l = reinterpret_cast<float4*>(Ulds);
        #pragma unroll
        for (int r = 0; r < 8; ++r) l[r * 256 + tid] = g[r * 256 + tid];
    }
    if (tid < HN) h[0][tid] = 0.0f;
    __syncthreads();

    for (int c = 0; c < NCH; ++c) {
        const bool has_next = (c + 1 < NCH);
        if (SYNC && has_next) wait_chunk(cnt, c + 1);

        // Issue-early: next chunk into registers; in flight across the chunk.
        float4 st[8];
        {
            const float4* gsrc = reinterpret_cast<const float4*>(
                U + (has_next ? (c + 1) : c) * CH * HN);
            #pragma unroll
            for (int r = 0; r < 8; ++r) st[r] = gsrc[r * 256 + tid];
        }

        for (int s2 = 0; s2 < CH; ++s2) {
            const int hc = s2 & 1;
            const float u_cur = Ulds[s2 * HN + oi_w];

            // 4 rotated b128 reads; scalar fmaf (compiler interleaves with
            // lgkmcnt — R13 showed asm pk_fma defeats this and loses).
            const float* base = &h[hc][jg * 16];
            float s0 = 0.f, s1 = 0.f, s2a = 0.f, s3 = 0.f;
            #pragma unroll
            for (int t = 0; t < 4; ++t) {
                const int krot = (t + rot) & 3;    // runtime only in the ADDRESS
                float4 hv = *reinterpret_cast<const float4*>(base + 4 * krot);
                s0  = fmaf(w[0][4*t+0], hv.x, s0);  s0  = fmaf(w[0][4*t+1], hv.y, s0);
                s0  = fmaf(w[0][4*t+2], hv.z, s0);  s0  = fmaf(w[0][4*t+3], hv.w, s0);
                s1  = fmaf(w[1][4*t+0], hv.x, s1);  s1  = fmaf(w[1][4*t+1], hv.y, s1);
                s1  = fmaf(w[1][4*t+2], hv.z, s1);  s1  = fmaf(w[1][4*t+3], hv.w, s1);
                s2a = fmaf(w[2][4*t+0], hv.x, s2a); s2a = fmaf(w[2][4*t+1], hv.y, s2a);
                s2a = fmaf(w[2][4*t+2], hv.z, s2a); s2a = fmaf(w[2][4*t+3], hv.w, s2a);
                s3  = fmaf(w[3][4*t+0], hv.x, s3);  s3  = fmaf(w[3][4*t+1], hv.y, s3);
                s3  = fmaf(w[3][4*t+2], hv.z, s3);  s3  = fmaf(w[3][4*t+3], hv.w, s3);
            }

            // 3-stage DPP reduce-scatter over the 8 jg lanes.
            const bool lo4 = !hi4;
            float t0 = lo4 ? s2a : s0;
            float t1 = lo4 ? s3  : s1;
            float x0 = (lo4 ? s0 : s2a) + dpp_xor4(t0, hi4);
            float x1 = (lo4 ? s1 : s3 ) + dpp_xor4(t1, hi4);
            const bool lo2 = (jg & 2) == 0;
            float t2 = lo2 ? x1 : x0;
            float z  = (lo2 ? x0 : x1) + dpp_xor2(t2);
            z += dpp_xor1(z);

            const float hn = fast_tanh(z + u_cur);
            if ((jg & 1) == 0) h[hc ^ 1][oi_w] = hn;
            lds_barrier();                     // lgkm-only: staging stays in flight
        }
        // After the final per-step barrier every wave's chunk-c reads are done
        // -> safe to overwrite the single panel. vmcnt wait on st is ~free.
        if (has_next) {
            float4* ldst = reinterpret_cast<float4*>(Ulds);
            #pragma unroll
            for (int r = 0; r < 8; ++r) ldst[r * 256 + tid] = st[r];
        }
        lds_barrier();                         // publish panel for chunk c+1
    }

    if (tid < HN) out[tid] = h[0][tid];        // each chunk ends at parity 0
}

// ---------------- kernels ----------------
__global__ __launch_bounds__(256) void fused_kernel(
    const float* __restrict__ event,  const int* __restrict__ lengths,
    const float* __restrict__ W_ih1,  const float* __restrict__ W_hh1,
    const float* __restrict__ b_ih1,  const float* __restrict__ b_hh1,
    const float* __restrict__ W_ih2,  const float* __restrict__ W_hh2,
    const float* __restrict__ b_ih2,  const float* __restrict__ b_hh2,
    float* __restrict__ U, float* __restrict__ out, unsigned* cnt)
{
    __shared__ float h[2][HN];                 // both paths
    __shared__ float ev[FN];                   // producer only
    __shared__ float Ulds[CH * HN + PADF];     // consumer panel + occupancy pad
                                               // (total ~82.3KB -> 1 block/CU:
                                               //  consumer gets a private CU)

    const int tid = threadIdx.x;
    if (blockIdx.x == 0) {
        net2_body<true>(tid, U, W_hh2, out, cnt, h, Ulds);
    } else {
        net1_body<true>(blockIdx.x - 1, tid, event, lengths, W_ih1, W_hh1,
                        b_ih1, b_hh1, W_ih2, b_ih2, b_hh2, U, cnt, h, ev);
    }
}

__global__ __launch_bounds__(256) void net1_only(
    const float* __restrict__ event,  const int* __restrict__ lengths,
    const float* __restrict__ W_ih1,  const float* __restrict__ W_hh1,
    const float* __restrict__ b_ih1,  const float* __restrict__ b_hh1,
    const float* __restrict__ W_ih2,  const float* __restrict__ b_ih2,
    const float* __restrict__ b_hh2,  float* __restrict__ U)
{
    __shared__ float h[2][HN];
    __shared__ float ev[FN];
    net1_body<false>(blockIdx.x, threadIdx.x, event, lengths, W_ih1, W_hh1,
                     b_ih1, b_hh1, W_ih2, b_ih2, b_hh2, U, nullptr, h, ev);
}

__global__ __launch_bounds__(256) void net2_only(
    const float* __restrict__ U, const float* __restrict__ W_hh2,
    float* __restrict__ out)
{
    __shared__ float h[2][HN];
    __shared__ float Ulds[CH * HN];
    net2_body<false>(threadIdx.x, U, W_hh2, out, nullptr, h, Ulds);
}

extern "C" void kernel_launch(void* const* d_in, const int* in_sizes, int n_in,
                              void* d_out, int out_size, void* d_ws, size_t ws_size,
                              hipStream_t stream)
{
    const float* event   = (const float*)d_in[0];
    const int*   lengths = (const int*)  d_in[1];
    const float* W_ih1   = (const float*)d_in[2];
    const float* W_hh1   = (const float*)d_in[3];
    const float* b_ih1   = (const float*)d_in[4];
    const float* b_hh1   = (const float*)d_in[5];
    const float* W_ih2   = (const float*)d_in[6];
    const float* W_hh2   = (const float*)d_in[7];
    const float* b_ih2   = (const float*)d_in[8];
    const float* b_hh2   = (const float*)d_in[9];
    float* out = (float*)d_out;                   // 128 floats
    float* U   = (float*)d_ws;                    // PN*HN floats = 2 MB
    unsigned* cnt = (unsigned*)(U + (size_t)PN * HN);

    const bool sync_ok =
        ws_size >= (size_t)PN * HN * sizeof(float) + NCH * sizeof(unsigned);

    if (sync_ok) {
        hipMemsetAsync(cnt, 0, NCH * sizeof(unsigned), stream);  // clear poison
        fused_kernel<<<dim3(PN + 1), dim3(256), 0, stream>>>(
            event, lengths, W_ih1, W_hh1, b_ih1, b_hh1,
            W_ih2, W_hh2, b_ih2, b_hh2, U, out, cnt);
    } else {
        net1_only<<<dim3(PN), dim3(256), 0, stream>>>(
            event, lengths, W_ih1, W_hh1, b_ih1, b_hh1, W_ih2, b_ih2, b_hh2, U);
        net2_only<<<dim3(1), dim3(256), 0, stream>>>(U, W_hh2, out);
    }
}